// Round 1
// baseline (630.464 us; speedup 1.0000x reference)
//
#include <hip/hip_runtime.h>
#include <cstdint>

// ---------------------------------------------------------------------------
// Gemma4 audio local attention, MI355X/gfx950.
// Pipeline: x->bf16 | W^T(+scales)->bf16 | sinusoid emb | QKV GEMM (bf16 MFMA,
// V stored transposed+padded) | pos GEMM | fused blocked local attention.
// ---------------------------------------------------------------------------

typedef __attribute__((ext_vector_type(8))) short s16x8;   // 8 x bf16 (4 VGPR)
typedef __attribute__((ext_vector_type(4))) float f32x4;
typedef __attribute__((ext_vector_type(4))) unsigned short u16x4;

#define MFMA16(A, B, C) __builtin_amdgcn_mfma_f32_16x16x32_bf16(A, B, C, 0, 0, 0)

__device__ __forceinline__ unsigned short f2bf(float f) {
  unsigned u = __float_as_uint(f);
  u += 0x7FFFu + ((u >> 16) & 1u);          // RNE
  return (unsigned short)(u >> 16);
}
__device__ __forceinline__ float bf2f(unsigned short s) {
  return __uint_as_float(((unsigned)s) << 16);
}

// async global->LDS, 16B per lane. LDS dest is wave-uniform base + lane*16,
// so per-thread dst must be linear in tid (it is: dst = base + chunk*16B).
__device__ __forceinline__ void gload16(const unsigned short* g, unsigned short* l) {
  __builtin_amdgcn_global_load_lds(
      (const __attribute__((address_space(1))) void*)(uintptr_t)g,
      (__attribute__((address_space(3))) void*)(unsigned)(uintptr_t)l,
      16, 0, 0);
}

// ---------------------------------------------------------------------------
// x f32 [16384][1536] -> bf16
__global__ void convert_x(const float4* __restrict__ x4, u16x4* __restrict__ o4) {
  int idx = blockIdx.x * 256 + threadIdx.x;
  #pragma unroll
  for (int i = 0; i < 12; ++i) {
    size_t k = (size_t)idx + (size_t)i * 524288;
    float4 v = x4[k];
    u16x4 o = {f2bf(v.x), f2bf(v.y), f2bf(v.z), f2bf(v.w)};
    o4[k] = o;
  }
}

// ---------------------------------------------------------------------------
// W^T with per-output-dim scales, bf16. Wt rows: [0,1536)=Wq^T*qscale,
// [1536,3072)=Wk^T*K_SCALE, [3072,4608)=Wv^T, [4608,6144)=Wpos^T.
__global__ void wt_kernel(const float* __restrict__ Wq, const float* __restrict__ Wk,
                          const float* __restrict__ Wv, const float* __restrict__ Wpos,
                          const float* __restrict__ pds, unsigned short* __restrict__ Wt) {
  int z = blockIdx.z;
  const float* W = (z == 0) ? Wq : (z == 1) ? Wk : (z == 2) ? Wv : Wpos;
  int k0 = blockIdx.x * 64, n0 = blockIdx.y * 64;
  __shared__ float tile[64][65];
  int tid = threadIdx.x;
  #pragma unroll
  for (int i = 0; i < 16; ++i) {
    int lin = i * 256 + tid, r = lin >> 6, c = lin & 63;
    tile[r][c] = W[(size_t)(k0 + r) * 1536 + n0 + c];
  }
  __syncthreads();
  const float LN2 = 0.6931471805599453f;
  #pragma unroll
  for (int i = 0; i < 16; ++i) {
    int lin = i * 256 + tid, r = lin >> 6, c = lin & 63;
    int nn = n0 + r;
    float scale = 1.f;
    if (z == 0) {
      float p = pds[nn & 127];
      float sp = (p > 20.f) ? p : log1pf(expf(p));
      scale = (0.08838834764831845f / LN2) * sp;   // Dh^-0.5/ln2 * softplus
    } else if (z == 1) {
      scale = 1.3132616875182228f / LN2;           // log1p(e)/ln2
    }
    Wt[(size_t)(z * 1536 + nn) * 1536 + k0 + c] = f2bf(tile[c][r] * scale);
  }
}

// ---------------------------------------------------------------------------
// sinusoidal embedding rows: emb[p][i], position = 127-p
__global__ void emb_kernel(unsigned short* __restrict__ emb) {
  int p = blockIdx.x, tid = threadIdx.x;
  float position = (float)(127 - p);
  float log_inc = logf(10000.f) / 767.f;
  #pragma unroll
  for (int j = 0; j < 6; ++j) {
    int i = tid + j * 256;
    int ii = (i < 768) ? i : i - 768;
    float arg = position * expf(-(float)ii * log_inc);
    float v = (i < 768) ? sinf(arg) : cosf(arg);
    emb[(size_t)p * 1536 + i] = f2bf(v);
  }
}

// ---------------------------------------------------------------------------
// 128x128x(K=1536) bf16 GEMM, BK=64, double-buffered LDS via global_load_lds,
// XOR-swizzled (chunk ^= row&7) for conflict-free ds_read_b128.
// mode 0: Y = X@[Wq|Wk|Wv]^T -> q,k(bf16, padded rows),v(transposed+padded)
// mode 1: Y = emb@Wpos^T -> posb[h][p][d]
__global__ __launch_bounds__(256, 2) void gemm_kernel(
    const unsigned short* __restrict__ A, const unsigned short* __restrict__ Bw,
    unsigned short* __restrict__ outq, unsigned short* __restrict__ outk,
    unsigned short* __restrict__ outv, unsigned short* __restrict__ outp,
    int nTN, int mode) {
  __shared__ __align__(16) unsigned short smem[2][16384];  // [buf][A 8192 | B 8192]
  const int tid = threadIdx.x;
  const int w = tid >> 6, l = tid & 63, g = l >> 4, li = l & 15;
  const int wr = w >> 1, wc = w & 1;
  int bid = blockIdx.x;
  if (mode == 0) bid = (bid & 7) * 576 + (bid >> 3);  // XCD swizzle (4608 % 8 == 0)
  const int tm = bid / nTN, tn = bid % nTN;

  const unsigned short* Ab = A + (size_t)tm * 128 * 1536;
  const unsigned short* Bb = Bw + (size_t)tn * 128 * 1536;

  f32x4 zero4 = {0.f, 0.f, 0.f, 0.f};
  f32x4 acc[4][4];
  #pragma unroll
  for (int i = 0; i < 4; ++i)
    #pragma unroll
    for (int j = 0; j < 4; ++j) acc[i][j] = zero4;

  auto stage = [&](int buf, int kk) {
    unsigned short* s = smem[buf];
    #pragma unroll
    for (int it = 0; it < 4; ++it) {
      int chunk = it * 256 + tid;
      int r = chunk >> 3, cs = chunk & 7;
      gload16(Ab + (size_t)r * 1536 + kk * 64 + ((cs ^ (r & 7)) << 3), s + chunk * 8);
    }
    #pragma unroll
    for (int it = 0; it < 4; ++it) {
      int chunk = it * 256 + tid;
      int r = chunk >> 3, cs = chunk & 7;
      gload16(Bb + (size_t)r * 1536 + kk * 64 + ((cs ^ (r & 7)) << 3),
              s + 8192 + chunk * 8);
    }
  };

  stage(0, 0);
  __syncthreads();
  for (int t = 0; t < 24; ++t) {
    if (t < 23) stage((t + 1) & 1, t + 1);
    const unsigned short* s = smem[t & 1];
    #pragma unroll
    for (int ks = 0; ks < 2; ++ks) {
      s16x8 af[4], bfm[4];
      #pragma unroll
      for (int mi = 0; mi < 4; ++mi) {
        int ar = wr * 64 + mi * 16 + li;
        int ch = (ks * 4 + g) ^ (ar & 7);
        af[mi] = *(const s16x8*)(s + ar * 64 + ch * 8);
      }
      #pragma unroll
      for (int ni = 0; ni < 4; ++ni) {
        int br = wc * 64 + ni * 16 + li;
        int ch = (ks * 4 + g) ^ (br & 7);
        bfm[ni] = *(const s16x8*)(s + 8192 + br * 64 + ch * 8);
      }
      #pragma unroll
      for (int mi = 0; mi < 4; ++mi)
        #pragma unroll
        for (int ni = 0; ni < 4; ++ni)
          acc[mi][ni] = MFMA16(af[mi], bfm[ni], acc[mi][ni]);
    }
    __syncthreads();
  }

  // epilogue: C/D layout col=lane&15, row=(lane>>4)*4+reg
  #pragma unroll
  for (int mi = 0; mi < 4; ++mi) {
    int mrow = tm * 128 + wr * 64 + mi * 16 + g * 4;
    #pragma unroll
    for (int ni = 0; ni < 4; ++ni) {
      int ncol = tn * 128 + wc * 64 + ni * 16 + li;
      f32x4 v4 = acc[mi][ni];
      if (mode == 1) {
        int hh = ncol >> 7, dd = ncol & 127;
        #pragma unroll
        for (int r = 0; r < 4; ++r)
          outp[((size_t)hh * 128 + (mrow + r)) * 128 + dd] = f2bf(v4[r]);
      } else if (ncol < 1536) {
        #pragma unroll
        for (int r = 0; r < 4; ++r)
          outq[(size_t)(mrow + r) * 1536 + ncol] = f2bf(v4[r]);
      } else if (ncol < 3072) {
        int bb = mrow >> 12, tt = mrow & 4095, nc = ncol - 1536;
        #pragma unroll
        for (int r = 0; r < 4; ++r)
          outk[((size_t)bb * 4224 + 127 + tt + r) * 1536 + nc] = f2bf(v4[r]);
      } else {
        int bb = mrow >> 12, tt = mrow & 4095, nc = ncol - 3072;
        size_t vo = ((size_t)(bb * 12 + (nc >> 7)) * 128 + (nc & 127)) * 4352 + 127 + tt;
        #pragma unroll
        for (int r = 0; r < 4; ++r) outv[vo + r] = f2bf(v4[r]);
      }
    }
  }
}

// ---------------------------------------------------------------------------
// Fused blocked local attention. 1 block = (b,h,n) 128-query tile, 4 waves,
// each wave owns 32 q-rows + its own 16KB LDS slice (no __syncthreads).
__global__ __launch_bounds__(256, 2) void attn_kernel(
    const unsigned short* __restrict__ qb, const unsigned short* __restrict__ kb,
    const unsigned short* __restrict__ vt, const unsigned short* __restrict__ posb,
    float* __restrict__ out) {
  __shared__ __align__(16) unsigned short smem[4 * 8192];  // 64KB, per-wave 8192 elems
  const int tid = threadIdx.x;
  const int w = tid >> 6, l = tid & 63, g = l >> 4, li = l & 15;
  const int bid = blockIdx.x;
  const int n = bid & 31, h = (bid >> 5) % 12, b = bid / 384;
  unsigned short* my = smem + w * 8192;

  // Q fragments (shared by QP and QK; k-dim contiguous bf16x8)
  s16x8 aq[2][4];
  const unsigned short* qbase =
      qb + ((size_t)(b * 4096 + n * 128 + w * 32)) * 1536 + h * 128;
  #pragma unroll
  for (int mt = 0; mt < 2; ++mt)
    #pragma unroll
    for (int kt = 0; kt < 4; ++kt)
      aq[mt][kt] = *(const s16x8*)(qbase + (size_t)(mt * 16 + li) * 1536 + kt * 32 + g * 8);

  // ---- QP = Q * pos^T  -> LDS rows[0,32) stride 136 (bf16)
  const unsigned short* pb = posb + (size_t)h * 128 * 128;
  #pragma unroll
  for (int pt = 0; pt < 8; ++pt) {
    s16x8 bp[4];
    #pragma unroll
    for (int kt = 0; kt < 4; ++kt)
      bp[kt] = *(const s16x8*)(pb + (size_t)(pt * 16 + li) * 128 + kt * 32 + g * 8);
    f32x4 a0 = {0.f, 0.f, 0.f, 0.f}, a1 = {0.f, 0.f, 0.f, 0.f};
    #pragma unroll
    for (int kt = 0; kt < 4; ++kt) {
      a0 = MFMA16(aq[0][kt], bp[kt], a0);
      a1 = MFMA16(aq[1][kt], bp[kt], a1);
    }
    #pragma unroll
    for (int r = 0; r < 4; ++r) {
      my[(g * 4 + r) * 136 + pt * 16 + li] = f2bf(a0[r]);
      my[(16 + g * 4 + r) * 136 + pt * 16 + li] = f2bf(a1[r]);
    }
  }

  // ---- S = Q*K^T. K padded: [b][4224][1536], physical row = n*128 + c
  f32x4 S[2][16];
  const unsigned short* kbase =
      kb + ((size_t)b * 4224 + n * 128) * 1536 + h * 128 + g * 8;
  #pragma unroll
  for (int ct = 0; ct < 16; ++ct) {
    const unsigned short* kr = kbase + (size_t)(ct * 16 + li) * 1536;
    s16x8 b0 = *(const s16x8*)(kr);
    s16x8 b1 = *(const s16x8*)(kr + 32);
    s16x8 b2 = *(const s16x8*)(kr + 64);
    s16x8 b3 = *(const s16x8*)(kr + 96);
    f32x4 s0 = {0.f, 0.f, 0.f, 0.f}, s1 = {0.f, 0.f, 0.f, 0.f};
    s0 = MFMA16(aq[0][0], b0, s0); s1 = MFMA16(aq[1][0], b0, s1);
    s0 = MFMA16(aq[0][1], b1, s0); s1 = MFMA16(aq[1][1], b1, s1);
    s0 = MFMA16(aq[0][2], b2, s0); s1 = MFMA16(aq[1][2], b2, s1);
    s0 = MFMA16(aq[0][3], b3, s0); s1 = MFMA16(aq[1][3], b3, s1);
    S[0][ct] = s0; S[1][ct] = s1;
  }

  // ---- bd add (XL shift: S[q,c] += QP[q,c-q]) + softcap + mask + row max
  float mrow[2][4];
  #pragma unroll
  for (int mt = 0; mt < 2; ++mt)
    #pragma unroll
    for (int r = 0; r < 4; ++r) mrow[mt][r] = -3e38f;

  #pragma unroll
  for (int mt = 0; mt < 2; ++mt) {
    #pragma unroll
    for (int ct = 0; ct < 16; ++ct) {
      #pragma unroll
      for (int r = 0; r < 4; ++r) {
        int lrow = mt * 16 + g * 4 + r;        // wave-local q row
        int qq = w * 32 + lrow;                // block-local q row
        int cc = ct * 16 + li;                 // context col
        int p = cc - qq;
        bool win = ((unsigned)p < 128u);       // causal window
        float sv = S[mt][ct][r];
        if (win) sv += bf2f(my[lrow * 136 + p]);
        float e2 = exp2f(sv * 0.0577078016355585f);   // (2/50)*log2(e)
        sv = 50.f * (e2 - 1.f) / (e2 + 1.f);          // 50*tanh(s/50)
        bool vld = win && (n * 128 + cc >= 127);      // t >= 0
        sv = vld ? sv : -3e38f;                       // (also kills NaN from pad-K)
        S[mt][ct][r] = sv;
        mrow[mt][r] = fmaxf(mrow[mt][r], sv);
      }
    }
  }

  // ---- softmax + write P (bf16, XOR-swizzled rows, overwrites QP region —
  //      all QP reads completed above; DS ops are in-order per wave)
  #pragma unroll
  for (int mt = 0; mt < 2; ++mt) {
    #pragma unroll
    for (int r = 0; r < 4; ++r) {
      float m_ = mrow[mt][r];
      #pragma unroll
      for (int d = 1; d < 16; d <<= 1) m_ = fmaxf(m_, __shfl_xor(m_, d));
      float sum = 0.f;
      #pragma unroll
      for (int ct = 0; ct < 16; ++ct) {
        float e = exp2f((S[mt][ct][r] - m_) * 1.4426950408889634f);
        S[mt][ct][r] = e;
        sum += e;
      }
      #pragma unroll
      for (int d = 1; d < 16; d <<= 1) sum += __shfl_xor(sum, d);
      float inv = 1.f / sum;
      int lrow = mt * 16 + g * 4 + r;
      #pragma unroll
      for (int ct = 0; ct < 16; ++ct) {
        int ch = (ct * 2 + (li >> 3)) ^ (lrow & 7);
        my[lrow * 256 + ch * 8 + (li & 7)] = f2bf(S[mt][ct][r] * inv);
      }
    }
  }

  // ---- O = P*V. V^T padded: [b][h][j][4352], col = n*128 + c (16B aligned,
  //      pads are zero so masked columns contribute exactly 0).
  s16x8 pa[2][8];
  #pragma unroll
  for (int mt = 0; mt < 2; ++mt)
    #pragma unroll
    for (int kt = 0; kt < 8; ++kt) {
      int row = mt * 16 + li;
      int ch = (kt * 4 + g) ^ (row & 7);
      pa[mt][kt] = *(const s16x8*)(my + row * 256 + ch * 8);
    }
  const unsigned short* vbase =
      vt + ((size_t)(b * 12 + h) * 128) * 4352 + n * 128 + g * 8;
  #pragma unroll
  for (int jt = 0; jt < 8; ++jt) {
    const unsigned short* vr = vbase + (size_t)(jt * 16 + li) * 4352;
    f32x4 o0 = {0.f, 0.f, 0.f, 0.f}, o1 = {0.f, 0.f, 0.f, 0.f};
    #pragma unroll
    for (int kt = 0; kt < 8; ++kt) {
      s16x8 bv = *(const s16x8*)(vr + kt * 32);
      o0 = MFMA16(pa[0][kt], bv, o0);
      o1 = MFMA16(pa[1][kt], bv, o1);
    }
    #pragma unroll
    for (int r = 0; r < 4; ++r) {
      int q0 = w * 32 + g * 4 + r;
      size_t base0 = (((size_t)b * 4096 + n * 128 + q0) * 12 + h) * 128 + jt * 16 + li;
      out[base0] = o0[r];
      out[base0 + (size_t)16 * 12 * 128] = o1[r];  // mt=1 rows (+16 t)
    }
  }
}

// ---------------------------------------------------------------------------
extern "C" void kernel_launch(void* const* d_in, const int* in_sizes, int n_in,
                              void* d_out, int out_size, void* d_ws, size_t ws_size,
                              hipStream_t stream) {
  const float* x = (const float*)d_in[0];
  const float* Wq = (const float*)d_in[1];
  const float* Wk = (const float*)d_in[2];
  const float* Wv = (const float*)d_in[3];
  const float* Wpos = (const float*)d_in[4];
  const float* pds = (const float*)d_in[5];
  float* out = (float*)d_out;

  char* ws = (char*)d_ws;
  unsigned short* xb   = (unsigned short*)(ws);              // 16384*1536 bf16
  unsigned short* Wt   = (unsigned short*)(ws + 50331648);   // 6144*1536 bf16
  unsigned short* emb  = (unsigned short*)(ws + 69206016);   // 128*1536 bf16
  unsigned short* posb = (unsigned short*)(ws + 69599232);   // 12*128*128 bf16
  unsigned short* kbuf = (unsigned short*)(ws + 69992448);   // 4*4224*1536 bf16 (padded)
  unsigned short* vtb  = (unsigned short*)(ws + 121896960);  // 4*12*128*4352 bf16 (padded)
  unsigned short* qbuf = (unsigned short*)(ws + 175374336);  // 16384*1536 bf16
  if (ws_size < 225705984) return;

  // zero V^T (pads must be true zeros; interior is overwritten by the GEMM)
  hipMemsetAsync(vtb, 0, (size_t)4 * 12 * 128 * 4352 * 2, stream);

  convert_x<<<2048, 256, 0, stream>>>((const float4*)x, (u16x4*)xb);
  wt_kernel<<<dim3(24, 24, 4), 256, 0, stream>>>(Wq, Wk, Wv, Wpos, pds, Wt);
  emb_kernel<<<128, 256, 0, stream>>>(emb);
  gemm_kernel<<<4608, 256, 0, stream>>>(xb, Wt, qbuf, kbuf, vtb, posb, 36, 0);
  gemm_kernel<<<12, 256, 0, stream>>>(emb, Wt + (size_t)4608 * 1536,
                                      qbuf, kbuf, vtb, posb, 12, 1);
  attn_kernel<<<1536, 256, 0, stream>>>(qbuf, kbuf, vtb, posb, out);
}

// Round 2
// 481.180 us; speedup vs baseline: 1.3102x; 1.3102x over previous
//
#include <hip/hip_runtime.h>
#include <cstdint>

// ---------------------------------------------------------------------------
// Gemma4 audio local attention, MI355X/gfx950.
// Pipeline: x->bf16 | W^T(+scales)->bf16 | sinusoid emb | QKV GEMM (bf16 MFMA,
// per-head layouts: q[b][h][t][d], k[b][h][tp][d], v^T[b][h][d][tp]) |
// pos GEMM | fused blocked local attention (LDS-staged K/V, 8 waves/block).
// ---------------------------------------------------------------------------

typedef __attribute__((ext_vector_type(8))) short s16x8;   // 8 x bf16 (4 VGPR)
typedef __attribute__((ext_vector_type(4))) float f32x4;
typedef __attribute__((ext_vector_type(4))) unsigned short u16x4;

#define MFMA16(A, B, C) __builtin_amdgcn_mfma_f32_16x16x32_bf16(A, B, C, 0, 0, 0)

__device__ __forceinline__ unsigned short f2bf(float f) {
  unsigned u = __float_as_uint(f);
  u += 0x7FFFu + ((u >> 16) & 1u);          // RNE
  return (unsigned short)(u >> 16);
}
__device__ __forceinline__ float bf2f(unsigned short s) {
  return __uint_as_float(((unsigned)s) << 16);
}

// async global->LDS, 16B per lane. LDS dest is wave-uniform base + lane*16
// (linear in tid); global source is per-lane (pre-swizzled there).
__device__ __forceinline__ void gload16(const unsigned short* g, unsigned short* l) {
  __builtin_amdgcn_global_load_lds(
      (const __attribute__((address_space(1))) void*)(uintptr_t)g,
      (__attribute__((address_space(3))) void*)(unsigned)(uintptr_t)l,
      16, 0, 0);
}

// ---------------------------------------------------------------------------
// x f32 [16384][1536] -> bf16
__global__ void convert_x(const float4* __restrict__ x4, u16x4* __restrict__ o4) {
  int idx = blockIdx.x * 256 + threadIdx.x;
  #pragma unroll
  for (int i = 0; i < 12; ++i) {
    size_t k = (size_t)idx + (size_t)i * 524288;
    float4 v = x4[k];
    u16x4 o = {f2bf(v.x), f2bf(v.y), f2bf(v.z), f2bf(v.w)};
    o4[k] = o;
  }
}

// ---------------------------------------------------------------------------
// W^T with per-output-dim scales, bf16. Wt rows: [0,1536)=Wq^T*qscale,
// [1536,3072)=Wk^T*K_SCALE, [3072,4608)=Wv^T, [4608,6144)=Wpos^T.
__global__ void wt_kernel(const float* __restrict__ Wq, const float* __restrict__ Wk,
                          const float* __restrict__ Wv, const float* __restrict__ Wpos,
                          const float* __restrict__ pds, unsigned short* __restrict__ Wt) {
  int z = blockIdx.z;
  const float* W = (z == 0) ? Wq : (z == 1) ? Wk : (z == 2) ? Wv : Wpos;
  int k0 = blockIdx.x * 64, n0 = blockIdx.y * 64;
  __shared__ float tile[64][65];
  int tid = threadIdx.x;
  #pragma unroll
  for (int i = 0; i < 16; ++i) {
    int lin = i * 256 + tid, r = lin >> 6, c = lin & 63;
    tile[r][c] = W[(size_t)(k0 + r) * 1536 + n0 + c];
  }
  __syncthreads();
  const float LN2 = 0.6931471805599453f;
  #pragma unroll
  for (int i = 0; i < 16; ++i) {
    int lin = i * 256 + tid, r = lin >> 6, c = lin & 63;
    int nn = n0 + r;
    float scale = 1.f;
    if (z == 0) {
      float p = pds[nn & 127];
      float sp = (p > 20.f) ? p : log1pf(expf(p));
      scale = (0.08838834764831845f / LN2) * sp;   // Dh^-0.5/ln2 * softplus
    } else if (z == 1) {
      scale = 1.3132616875182228f / LN2;           // log1p(e)/ln2
    }
    Wt[(size_t)(z * 1536 + nn) * 1536 + k0 + c] = f2bf(tile[c][r] * scale);
  }
}

// ---------------------------------------------------------------------------
// sinusoidal embedding rows: emb[p][i], position = 127-p
__global__ void emb_kernel(unsigned short* __restrict__ emb) {
  int p = blockIdx.x, tid = threadIdx.x;
  float position = (float)(127 - p);
  float log_inc = logf(10000.f) / 767.f;
  #pragma unroll
  for (int j = 0; j < 6; ++j) {
    int i = tid + j * 256;
    int ii = (i < 768) ? i : i - 768;
    float arg = position * expf(-(float)ii * log_inc);
    float v = (i < 768) ? sinf(arg) : cosf(arg);
    emb[(size_t)p * 1536 + i] = f2bf(v);
  }
}

// ---------------------------------------------------------------------------
// 128x128x(K=1536) bf16 GEMM, BK=64, double-buffered LDS via global_load_lds,
// XOR-swizzled (chunk ^= row&7) for conflict-free ds_read_b128.
// mode 0: Y = X@[Wq|Wk|Wv]^T -> q[b][h][t][d], k[b][h][127+t][d], v^T[b][h][d][127+t]
// mode 1: Y = emb@Wpos^T -> posb[h][p][d]
__global__ __launch_bounds__(256, 2) void gemm_kernel(
    const unsigned short* __restrict__ A, const unsigned short* __restrict__ Bw,
    unsigned short* __restrict__ outq, unsigned short* __restrict__ outk,
    unsigned short* __restrict__ outv, unsigned short* __restrict__ outp,
    int nTN, int mode) {
  __shared__ __align__(16) unsigned short smem[2][16384];  // [buf][A 8192 | B 8192]
  const int tid = threadIdx.x;
  const int w = tid >> 6, l = tid & 63, g = l >> 4, li = l & 15;
  const int wr = w >> 1, wc = w & 1;
  int bid = blockIdx.x;
  if (mode == 0) bid = (bid & 7) * 576 + (bid >> 3);  // XCD swizzle (4608 % 8 == 0)
  const int tm = bid / nTN, tn = bid % nTN;

  const unsigned short* Ab = A + (size_t)tm * 128 * 1536;
  const unsigned short* Bb = Bw + (size_t)tn * 128 * 1536;

  f32x4 zero4 = {0.f, 0.f, 0.f, 0.f};
  f32x4 acc[4][4];
  #pragma unroll
  for (int i = 0; i < 4; ++i)
    #pragma unroll
    for (int j = 0; j < 4; ++j) acc[i][j] = zero4;

  auto stage = [&](int buf, int kk) {
    unsigned short* s = smem[buf];
    #pragma unroll
    for (int it = 0; it < 4; ++it) {
      int chunk = it * 256 + tid;
      int r = chunk >> 3, cs = chunk & 7;
      gload16(Ab + (size_t)r * 1536 + kk * 64 + ((cs ^ (r & 7)) << 3), s + chunk * 8);
    }
    #pragma unroll
    for (int it = 0; it < 4; ++it) {
      int chunk = it * 256 + tid;
      int r = chunk >> 3, cs = chunk & 7;
      gload16(Bb + (size_t)r * 1536 + kk * 64 + ((cs ^ (r & 7)) << 3),
              s + 8192 + chunk * 8);
    }
  };

  stage(0, 0);
  __syncthreads();
  for (int t = 0; t < 24; ++t) {
    if (t < 23) stage((t + 1) & 1, t + 1);
    const unsigned short* s = smem[t & 1];
    #pragma unroll
    for (int ks = 0; ks < 2; ++ks) {
      s16x8 af[4], bfm[4];
      #pragma unroll
      for (int mi = 0; mi < 4; ++mi) {
        int ar = wr * 64 + mi * 16 + li;
        int ch = (ks * 4 + g) ^ (ar & 7);
        af[mi] = *(const s16x8*)(s + ar * 64 + ch * 8);
      }
      #pragma unroll
      for (int ni = 0; ni < 4; ++ni) {
        int br = wc * 64 + ni * 16 + li;
        int ch = (ks * 4 + g) ^ (br & 7);
        bfm[ni] = *(const s16x8*)(s + 8192 + br * 64 + ch * 8);
      }
      #pragma unroll
      for (int mi = 0; mi < 4; ++mi)
        #pragma unroll
        for (int ni = 0; ni < 4; ++ni)
          acc[mi][ni] = MFMA16(af[mi], bfm[ni], acc[mi][ni]);
    }
    __syncthreads();
  }

  // epilogue: C/D layout col=lane&15, row=(lane>>4)*4+reg
  #pragma unroll
  for (int mi = 0; mi < 4; ++mi) {
    int mrow = tm * 128 + wr * 64 + mi * 16 + g * 4;
    #pragma unroll
    for (int ni = 0; ni < 4; ++ni) {
      int ncol = tn * 128 + wc * 64 + ni * 16 + li;
      f32x4 v4 = acc[mi][ni];
      if (mode == 1) {
        int hh = ncol >> 7, dd = ncol & 127;
        #pragma unroll
        for (int r = 0; r < 4; ++r)
          outp[((size_t)hh * 128 + (mrow + r)) * 128 + dd] = f2bf(v4[r]);
      } else if (ncol < 1536) {
        int bb = mrow >> 12, tt = mrow & 4095, hh = ncol >> 7, dd = ncol & 127;
        #pragma unroll
        for (int r = 0; r < 4; ++r)
          outq[((size_t)(bb * 12 + hh) * 4096 + tt + r) * 128 + dd] = f2bf(v4[r]);
      } else if (ncol < 3072) {
        int bb = mrow >> 12, tt = mrow & 4095;
        int nc = ncol - 1536, hh = nc >> 7, dd = nc & 127;
        #pragma unroll
        for (int r = 0; r < 4; ++r)
          outk[((size_t)(bb * 12 + hh) * 4224 + 127 + tt + r) * 128 + dd] = f2bf(v4[r]);
      } else {
        int bb = mrow >> 12, tt = mrow & 4095;
        int nc = ncol - 3072, hh = nc >> 7, dd = nc & 127;
        size_t vo = ((size_t)(bb * 12 + hh) * 128 + dd) * 4352 + 127 + tt;
        #pragma unroll
        for (int r = 0; r < 4; ++r) outv[vo + r] = f2bf(v4[r]);
      }
    }
  }
}

// ---------------------------------------------------------------------------
// Fused blocked local attention. 1 block = (b,h,n) 128-query tile, 8 waves x
// 16 q-rows. K/V staged cooperatively into a 32KB LDS buffer (time-shared
// K0,K1,V0,V1) via global_load_lds with XOR-swizzled source; QP then P live
// in a second 32KB region (wave-private rows, no barrier needed there).
__global__ __launch_bounds__(512, 4) void attn_kernel(
    const unsigned short* __restrict__ qb, const unsigned short* __restrict__ kb,
    const unsigned short* __restrict__ vt, const unsigned short* __restrict__ posb,
    float* __restrict__ out) {
  __shared__ __align__(16) unsigned short kv[16384];    // 32KB: K/V half-tiles
  __shared__ __align__(16) unsigned short pbuf[16384];  // 32KB: QP then P
  const int tid = threadIdx.x;
  const int w = tid >> 6, l = tid & 63, g = l >> 4, li = l & 15;
  int bid = blockIdx.x;
  bid = (bid & 7) * 192 + (bid >> 3);   // XCD swizzle: adjacent n share K/V
  const int n = bid & 31, h = (bid >> 5) % 12, b = bid / 384;
  const int qrow0 = w * 16;             // wave-local q base (block-local)

  // ---- stage lambdas: LDS row = local row; source slot pre-swizzled so a
  //      swizzled ds_read (slot ^ ((row&7)<<1)) returns linear data.
  auto stageK = [&](int half) {
    const unsigned short* kb0 =
        kb + ((size_t)(b * 12 + h) * 4224 + n * 128 + half * 128) * 128;
    #pragma unroll
    for (int it = 0; it < 4; ++it) {
      int chunk = it * 512 + tid;
      int row = chunk >> 4, sl = chunk & 15;
      gload16(kb0 + row * 128 + ((sl ^ ((row & 7) << 1)) << 3), kv + chunk * 8);
    }
  };
  auto stageV = [&](int half) {
    const unsigned short* vb0 =
        vt + (size_t)(b * 12 + h) * 128 * 4352 + n * 128 + half * 128;
    #pragma unroll
    for (int it = 0; it < 4; ++it) {
      int chunk = it * 512 + tid;
      int row = chunk >> 4, sl = chunk & 15;
      gload16(vb0 + (size_t)row * 4352 + ((sl ^ ((row & 7) << 1)) << 3),
              kv + chunk * 8);
    }
  };

  stageK(0);  // issue ASAP; QP compute below overlaps the loads

  // ---- Q fragments (A-frag: row=li, k = kt*32+g*8)
  s16x8 aq[4];
  const unsigned short* qbase =
      qb + ((size_t)(b * 12 + h) * 4096 + n * 128 + qrow0 + li) * 128 + g * 8;
  #pragma unroll
  for (int kt = 0; kt < 4; ++kt) aq[kt] = *(const s16x8*)(qbase + kt * 32);

  // ---- QP = Q * pos^T -> pbuf rows [qrow0, qrow0+16), linear [q][p]
  const unsigned short* pb = posb + (size_t)h * 128 * 128;
  #pragma unroll
  for (int pt = 0; pt < 8; ++pt) {
    f32x4 a = {0.f, 0.f, 0.f, 0.f};
    #pragma unroll
    for (int kt = 0; kt < 4; ++kt) {
      s16x8 bp = *(const s16x8*)(pb + (pt * 16 + li) * 128 + kt * 32 + g * 8);
      a = MFMA16(aq[kt], bp, a);
    }
    #pragma unroll
    for (int r = 0; r < 4; ++r)
      pbuf[(qrow0 + g * 4 + r) * 128 + pt * 16 + li] = f2bf(a[r]);
  }

  f32x4 S[16];

  // ---- S half: QK^T from LDS (B-frag: col=ctx=li-row, k contiguous)
  auto sHalf = [&](int half) {
    #pragma unroll
    for (int c8 = 0; c8 < 8; ++c8) {
      int rowc = c8 * 16 + li;
      f32x4 s = {0.f, 0.f, 0.f, 0.f};
      #pragma unroll
      for (int kt = 0; kt < 4; ++kt) {
        int slot = (kt * 4 + g) ^ ((rowc & 7) << 1);
        s16x8 bk = *(const s16x8*)(kv + rowc * 128 + slot * 8);
        s = MFMA16(aq[kt], bk, s);
      }
      S[half * 8 + c8] = s;
    }
    // bd add (XL shift: S[q,c] += QP[q,c-q]) + softcap + mask
    #pragma unroll
    for (int c8 = 0; c8 < 8; ++c8) {
      int ct = half * 8 + c8;
      #pragma unroll
      for (int r = 0; r < 4; ++r) {
        int qq = qrow0 + g * 4 + r;       // block-local q
        int cc = ct * 16 + li;            // block-local ctx
        int p = cc - qq;
        bool win = ((unsigned)p < 128u);
        float bd = bf2f(pbuf[qq * 128 + (p & 127)]);
        float sv = S[ct][r] + (win ? bd : 0.f);
        float e2 = exp2f(sv * 0.0577078016355585f);   // (2/50)*log2(e)
        sv = 50.f - 100.f / (e2 + 1.f);               // 50*tanh(s/50), NaN-free
        bool vld = win && (n * 128 + cc >= 127);      // key t >= 0
        S[ct][r] = vld ? sv : -3e38f;
      }
    }
  };

  __syncthreads();          // K0 resident
  sHalf(0);
  __syncthreads();          // all waves done reading K0
  stageK(1);
  __syncthreads();          // K1 resident
  sHalf(1);

  // ---- softmax (full row in regs; every row has >=1 valid -> m > -3e38)
  float inv_[4], mr_[4];
  #pragma unroll
  for (int r = 0; r < 4; ++r) {
    float m_ = -3e38f;
    #pragma unroll
    for (int ct = 0; ct < 16; ++ct) m_ = fmaxf(m_, S[ct][r]);
    #pragma unroll
    for (int d = 1; d < 16; d <<= 1) m_ = fmaxf(m_, __shfl_xor(m_, d));
    float sum = 0.f;
    #pragma unroll
    for (int ct = 0; ct < 16; ++ct) {
      float e = exp2f((S[ct][r] - m_) * 1.4426950408889634f);
      S[ct][r] = e;
      sum += e;
    }
    #pragma unroll
    for (int d = 1; d < 16; d <<= 1) sum += __shfl_xor(sum, d);
    inv_[r] = 1.f / sum;
    mr_[r] = m_;
  }
  (void)mr_;

  // ---- P write (bf16, swizzled slots, own rows) + pa read + PV per half
  f32x4 O[8];
  #pragma unroll
  for (int jt = 0; jt < 8; ++jt) O[jt] = f32x4{0.f, 0.f, 0.f, 0.f};
  s16x8 pa[4];

  auto writeP = [&](int half) {
    #pragma unroll
    for (int c8 = 0; c8 < 8; ++c8)
      #pragma unroll
      for (int r = 0; r < 4; ++r) {
        int row = qrow0 + g * 4 + r;
        int slot = (c8 * 2 + (li >> 3)) ^ ((row & 7) << 1);
        pbuf[row * 128 + slot * 8 + (li & 7)] = f2bf(S[half * 8 + c8][r] * inv_[r]);
      }
  };
  auto readPA = [&]() {
    #pragma unroll
    for (int c = 0; c < 4; ++c) {
      int row = qrow0 + li;
      int slot = (c * 4 + g) ^ ((li & 7) << 1);
      pa[c] = *(const s16x8*)(pbuf + row * 128 + slot * 8);
    }
  };
  auto pvHalf = [&]() {
    #pragma unroll
    for (int jt = 0; jt < 8; ++jt) {
      int rowd = jt * 16 + li;
      #pragma unroll
      for (int c = 0; c < 4; ++c) {
        int slot = (c * 4 + g) ^ ((rowd & 7) << 1);
        s16x8 bv = *(const s16x8*)(kv + rowd * 128 + slot * 8);
        O[jt] = MFMA16(pa[c], bv, O[jt]);
      }
    }
  };

  __syncthreads();          // all waves done reading K1 (kv free for V0)
  stageV(0);
  writeP(0);                // pbuf own rows: QP (own) no longer needed
  readPA();
  __syncthreads();          // V0 resident
  pvHalf();
  __syncthreads();          // done reading V0
  stageV(1);
  writeP(1);
  readPA();
  __syncthreads();          // V1 resident
  pvHalf();

  // ---- store O (f32, out[b][t][h][d])
  #pragma unroll
  for (int jt = 0; jt < 8; ++jt)
    #pragma unroll
    for (int r = 0; r < 4; ++r) {
      int q = n * 128 + qrow0 + g * 4 + r;
      out[(((size_t)b * 4096 + q) * 12 + h) * 128 + jt * 16 + li] = O[jt][r];
    }
}

// ---------------------------------------------------------------------------
extern "C" void kernel_launch(void* const* d_in, const int* in_sizes, int n_in,
                              void* d_out, int out_size, void* d_ws, size_t ws_size,
                              hipStream_t stream) {
  const float* x = (const float*)d_in[0];
  const float* Wq = (const float*)d_in[1];
  const float* Wk = (const float*)d_in[2];
  const float* Wv = (const float*)d_in[3];
  const float* Wpos = (const float*)d_in[4];
  const float* pds = (const float*)d_in[5];
  float* out = (float*)d_out;

  char* ws = (char*)d_ws;
  unsigned short* xb   = (unsigned short*)(ws);              // 16384*1536 bf16
  unsigned short* Wt   = (unsigned short*)(ws + 50331648);   // 6144*1536 bf16
  unsigned short* emb  = (unsigned short*)(ws + 69206016);   // 128*1536 bf16
  unsigned short* posb = (unsigned short*)(ws + 69599232);   // 12*128*128 bf16
  unsigned short* kbuf = (unsigned short*)(ws + 69992448);   // 4*12*4224*128 bf16
  unsigned short* vtb  = (unsigned short*)(ws + 121896960);  // 4*12*128*4352 bf16
  unsigned short* qbuf = (unsigned short*)(ws + 175374336);  // 4*12*4096*128 bf16
  if (ws_size < 225705984) return;

  convert_x<<<2048, 256, 0, stream>>>((const float4*)x, (u16x4*)xb);
  wt_kernel<<<dim3(24, 24, 4), 256, 0, stream>>>(Wq, Wk, Wv, Wpos, pds, Wt);
  emb_kernel<<<128, 256, 0, stream>>>(emb);
  gemm_kernel<<<4608, 256, 0, stream>>>(xb, Wt, qbuf, kbuf, vtb, posb, 36, 0);
  gemm_kernel<<<12, 256, 0, stream>>>(emb, Wt + (size_t)4608 * 1536,
                                      qbuf, kbuf, vtb, posb, 12, 1);
  attn_kernel<<<1536, 512, 0, stream>>>(qbuf, kbuf, vtb, posb, out);
}

// Round 3
// 459.361 us; speedup vs baseline: 1.3725x; 1.0475x over previous
//
#include <hip/hip_runtime.h>
#include <cstdint>

// ---------------------------------------------------------------------------
// Gemma4 audio local attention, MI355X/gfx950.
// Pipeline: x->bf16 | W^T(+scales)->bf16 | sinusoid emb | QKV GEMM (256x256
// 8-phase bf16 MFMA, per-head layouts q[b][h][t][d], k[b][h][tp][d],
// v^T[b][h][d][tp]) | pos GEMM (128x128) | fused blocked local attention.
// ---------------------------------------------------------------------------

typedef __attribute__((ext_vector_type(8))) short s16x8;   // 8 x bf16 (4 VGPR)
typedef __attribute__((ext_vector_type(4))) float f32x4;
typedef __attribute__((ext_vector_type(4))) unsigned short u16x4;

#define MFMA16(A, B, C) __builtin_amdgcn_mfma_f32_16x16x32_bf16(A, B, C, 0, 0, 0)

__device__ __forceinline__ unsigned short f2bf(float f) {
  unsigned u = __float_as_uint(f);
  u += 0x7FFFu + ((u >> 16) & 1u);          // RNE
  return (unsigned short)(u >> 16);
}
__device__ __forceinline__ float bf2f(unsigned short s) {
  return __uint_as_float(((unsigned)s) << 16);
}

// async global->LDS, 16B per lane. LDS dest is wave-uniform base + lane*16
// (linear in tid); global source is per-lane (pre-swizzled there).
__device__ __forceinline__ void gload16(const unsigned short* g, unsigned short* l) {
  __builtin_amdgcn_global_load_lds(
      (const __attribute__((address_space(1))) void*)(uintptr_t)g,
      (__attribute__((address_space(3))) void*)(unsigned)(uintptr_t)l,
      16, 0, 0);
}

// ---------------------------------------------------------------------------
// x f32 [16384][1536] -> bf16
__global__ void convert_x(const float4* __restrict__ x4, u16x4* __restrict__ o4) {
  int idx = blockIdx.x * 256 + threadIdx.x;
  #pragma unroll
  for (int i = 0; i < 12; ++i) {
    size_t k = (size_t)idx + (size_t)i * 524288;
    float4 v = x4[k];
    u16x4 o = {f2bf(v.x), f2bf(v.y), f2bf(v.z), f2bf(v.w)};
    o4[k] = o;
  }
}

// ---------------------------------------------------------------------------
// W^T with per-output-dim scales, bf16. Wt rows: [0,1536)=Wq^T*qscale,
// [1536,3072)=Wk^T*K_SCALE, [3072,4608)=Wv^T, [4608,6144)=Wpos^T.
__global__ void wt_kernel(const float* __restrict__ Wq, const float* __restrict__ Wk,
                          const float* __restrict__ Wv, const float* __restrict__ Wpos,
                          const float* __restrict__ pds, unsigned short* __restrict__ Wt) {
  int z = blockIdx.z;
  const float* W = (z == 0) ? Wq : (z == 1) ? Wk : (z == 2) ? Wv : Wpos;
  int k0 = blockIdx.x * 64, n0 = blockIdx.y * 64;
  __shared__ float tile[64][65];
  int tid = threadIdx.x;
  #pragma unroll
  for (int i = 0; i < 16; ++i) {
    int lin = i * 256 + tid, r = lin >> 6, c = lin & 63;
    tile[r][c] = W[(size_t)(k0 + r) * 1536 + n0 + c];
  }
  __syncthreads();
  const float LN2 = 0.6931471805599453f;
  #pragma unroll
  for (int i = 0; i < 16; ++i) {
    int lin = i * 256 + tid, r = lin >> 6, c = lin & 63;
    int nn = n0 + r;
    float scale = 1.f;
    if (z == 0) {
      float p = pds[nn & 127];
      float sp = (p > 20.f) ? p : log1pf(expf(p));
      scale = (0.08838834764831845f / LN2) * sp;   // Dh^-0.5/ln2 * softplus
    } else if (z == 1) {
      scale = 1.3132616875182228f / LN2;           // log1p(e)/ln2
    }
    Wt[(size_t)(z * 1536 + nn) * 1536 + k0 + c] = f2bf(tile[c][r] * scale);
  }
}

// ---------------------------------------------------------------------------
// sinusoidal embedding rows: emb[p][i], position = 127-p
__global__ void emb_kernel(unsigned short* __restrict__ emb) {
  int p = blockIdx.x, tid = threadIdx.x;
  float position = (float)(127 - p);
  float log_inc = logf(10000.f) / 767.f;
  #pragma unroll
  for (int j = 0; j < 6; ++j) {
    int i = tid + j * 256;
    int ii = (i < 768) ? i : i - 768;
    float arg = position * expf(-(float)ii * log_inc);
    float v = (i < 768) ? sinf(arg) : cosf(arg);
    emb[(size_t)p * 1536 + i] = f2bf(v);
  }
}

// ---------------------------------------------------------------------------
// st_16x32-swizzled LDS tile accessor. Tile = 256x64 bf16 stored as
// [row>>4][col>>5] subtiles of 1024B; within subtile byte ^= ((byte>>9)&1)<<5.
__device__ __forceinline__ const s16x8* ldsFrag(const unsigned short* tile,
                                                int row, int col) {
  int byte = ((((row >> 4) << 1) + (col >> 5)) << 10) +
             (((((row & 15) << 6) | ((col & 31) << 1))) ^ ((row & 8) << 2));
  return (const s16x8*)((const char*)tile + byte);
}

// One 8-phase quadrant: 4(+4) ds_read_b128, 1 half-tile stage, barrier,
// lgkmcnt(0), 16 MFMA under setprio, optional counted vmcnt, barrier.
template <int BB, int KS, int MH, bool CHECK, typename F>
__device__ __forceinline__ void gphase(const unsigned short* lds, int wm, int wn,
                                       int li, int g, f32x4 (&acc)[8][4],
                                       s16x8 (&bf)[4], F&& stage) {
  const unsigned short* At = lds + BB * 32768;
  const unsigned short* Bt = At + 16384;
  s16x8 af[4];
  #pragma unroll
  for (int fi = 0; fi < 4; ++fi)
    af[fi] = *ldsFrag(At, wm * 128 + MH * 64 + fi * 16 + li, KS * 32 + g * 8);
  if (MH == 0) {
    #pragma unroll
    for (int fj = 0; fj < 4; ++fj)
      bf[fj] = *ldsFrag(Bt, wn * 64 + fj * 16 + li, KS * 32 + g * 8);
  }
  stage();
  asm volatile("" ::: "memory");
  __builtin_amdgcn_s_barrier();
  asm volatile("s_waitcnt lgkmcnt(0)" ::: "memory");
  __builtin_amdgcn_s_setprio(1);
  #pragma unroll
  for (int fi = 0; fi < 4; ++fi)
    #pragma unroll
    for (int fj = 0; fj < 4; ++fj)
      acc[MH * 4 + fi][fj] = MFMA16(af[fi], bf[fj], acc[MH * 4 + fi][fj]);
  __builtin_amdgcn_s_setprio(0);
  if (CHECK) asm volatile("s_waitcnt vmcnt(2)" ::: "memory");
  asm volatile("" ::: "memory");
  __builtin_amdgcn_s_barrier();
  asm volatile("" ::: "memory");
}

// ---------------------------------------------------------------------------
// 256x256x(K=1536) bf16 GEMM, 8-phase schedule (T2+T3+T4+T5).
// Y = X@[Wq|Wk|Wv]^T -> q[b][h][t][d], k[b][h][127+t][d], v^T[b][h][d][127+t]
__global__ __launch_bounds__(512, 2) void gemm256_kernel(
    const unsigned short* __restrict__ A, const unsigned short* __restrict__ Bw,
    unsigned short* __restrict__ outq, unsigned short* __restrict__ outk,
    unsigned short* __restrict__ outv) {
  __shared__ __align__(16) unsigned short lds[65536];  // 128KB: 2x(A 32K + B 32K)
  const int tid = threadIdx.x;
  const int w = tid >> 6, l = tid & 63, g = l >> 4, li = l & 15;
  const int wm = w >> 2, wn = w & 3;

  // XCD-bijective swizzle (1152 % 8 == 0) + 8x6 supertiles for L2 locality
  int swz = (blockIdx.x & 7) * 144 + (blockIdx.x >> 3);
  int grp = swz / 48, idx = swz % 48;
  const int tm = (grp / 3) * 8 + idx / 6;    // 0..63
  const int tn = (grp % 3) * 6 + idx % 6;    // 0..17

  const unsigned short* Ab = A + (size_t)tm * 256 * 1536;
  const unsigned short* Bb = Bw + (size_t)tn * 256 * 1536;

  // stage one 128x64 half-tile: linear LDS dest, inverse-swizzled source
  auto stageHalf = [&](int dstE, const unsigned short* src, int row0, int k0) {
    #pragma unroll
    for (int it = 0; it < 2; ++it) {
      int q = it * 512 + tid;                 // 0..1023 chunks of 16B
      int off = (q & 63) << 4;                // byte within 1024B subtile
      off ^= ((off >> 9) & 1) << 5;
      int sub = q >> 6;
      int srow = ((sub >> 1) << 4) + (off >> 6);
      int scol = ((sub & 1) << 5) + ((off & 63) >> 1);
      gload16(src + (size_t)(row0 + srow) * 1536 + k0 + scol,
              (unsigned short*)lds + dstE + q * 8);
    }
  };

  f32x4 acc[8][4];
  #pragma unroll
  for (int i = 0; i < 8; ++i)
    #pragma unroll
    for (int j = 0; j < 4; ++j) acc[i][j] = f32x4{0.f, 0.f, 0.f, 0.f};
  s16x8 bf[4];

  // prologue: K-tile0 (buf0 full) + K-tile1.A0 (buf1); leave newest 2 in flight
  stageHalf(0,     Ab, 0,   0);
  stageHalf(8192,  Ab, 128, 0);
  stageHalf(16384, Bb, 0,   0);
  stageHalf(24576, Bb, 128, 0);
  stageHalf(32768, Ab, 0,   64);
  asm volatile("s_waitcnt vmcnt(2)" ::: "memory");
  __builtin_amdgcn_s_barrier();
  asm volatile("" ::: "memory");

  // 12 iters x 2 K-tiles. Phase->stage slots (region freed one phase earlier):
  //  p0 buf0(k0,m0) stage buf1.A1<-kt(b+1)   p4 buf1(k0,m0) stage buf0.A1<-kt(b+2)
  //  p1 buf0(k0,m1) stage buf1.B0            p5 buf1(k0,m1) stage buf0.B0
  //  p2 buf0(k1,m0) stage buf1.B1            p6 buf1(k1,m0) stage buf0.B1
  //  p3 buf0(k1,m1) stage buf0.A0<-kt(b+2)*  p7 buf1(k1,m1) stage buf1.A0<-kt(b+3)*
  //  (* = vmcnt(2) check; last iter's b+2/b+3 prefetches read adjacent ws, dead)
  for (int t = 0; t < 12; ++t) {
    const int k1 = (2 * t + 1) * 64, k2 = k1 + 64, k3 = k2 + 64;
    gphase<0,0,0,false>(lds, wm, wn, li, g, acc, bf, [&]{ stageHalf(40960, Ab, 128, k1); });
    gphase<0,0,1,false>(lds, wm, wn, li, g, acc, bf, [&]{ stageHalf(49152, Bb, 0,   k1); });
    gphase<0,1,0,false>(lds, wm, wn, li, g, acc, bf, [&]{ stageHalf(57344, Bb, 128, k1); });
    gphase<0,1,1,true >(lds, wm, wn, li, g, acc, bf, [&]{ stageHalf(0,     Ab, 0,   k2); });
    gphase<1,0,0,false>(lds, wm, wn, li, g, acc, bf, [&]{ stageHalf(8192,  Ab, 128, k2); });
    gphase<1,0,1,false>(lds, wm, wn, li, g, acc, bf, [&]{ stageHalf(16384, Bb, 0,   k2); });
    gphase<1,1,0,false>(lds, wm, wn, li, g, acc, bf, [&]{ stageHalf(24576, Bb, 128, k2); });
    gphase<1,1,1,true >(lds, wm, wn, li, g, acc, bf, [&]{ stageHalf(32768, Ab, 0,   k3); });
  }

  // epilogue scatter: C/D layout col=lane&15, row=(lane>>4)*4+reg
  #pragma unroll
  for (int mf = 0; mf < 8; ++mf) {
    int mrow = tm * 256 + wm * 128 + mf * 16 + g * 4;
    int bb_ = mrow >> 12, tt = mrow & 4095;
    #pragma unroll
    for (int fj = 0; fj < 4; ++fj) {
      int ncol = tn * 256 + wn * 64 + fj * 16 + li;
      f32x4 v4 = acc[mf][fj];
      if (ncol < 1536) {
        int hh = ncol >> 7, dd = ncol & 127;
        #pragma unroll
        for (int r = 0; r < 4; ++r)
          outq[((size_t)(bb_ * 12 + hh) * 4096 + tt + r) * 128 + dd] = f2bf(v4[r]);
      } else if (ncol < 3072) {
        int nc = ncol - 1536, hh = nc >> 7, dd = nc & 127;
        #pragma unroll
        for (int r = 0; r < 4; ++r)
          outk[((size_t)(bb_ * 12 + hh) * 4224 + 127 + tt + r) * 128 + dd] = f2bf(v4[r]);
      } else {
        int nc = ncol - 3072, hh = nc >> 7, dd = nc & 127;
        size_t vo = ((size_t)(bb_ * 12 + hh) * 128 + dd) * 4352 + 127 + tt;
        #pragma unroll
        for (int r = 0; r < 4; ++r) outv[vo + r] = f2bf(v4[r]);
      }
    }
  }
}

// ---------------------------------------------------------------------------
// 128x128x(K=1536) bf16 GEMM (m97 structure) — pos GEMM only (12 blocks).
// Y = emb@Wpos^T -> posb[h][p][d]
__global__ __launch_bounds__(256, 2) void gemm_kernel(
    const unsigned short* __restrict__ A, const unsigned short* __restrict__ Bw,
    unsigned short* __restrict__ outp, int nTN) {
  __shared__ __align__(16) unsigned short smem[2][16384];
  const int tid = threadIdx.x;
  const int w = tid >> 6, l = tid & 63, g = l >> 4, li = l & 15;
  const int wr = w >> 1, wc = w & 1;
  const int tm = blockIdx.x / nTN, tn = blockIdx.x % nTN;

  const unsigned short* Ab = A + (size_t)tm * 128 * 1536;
  const unsigned short* Bb = Bw + (size_t)tn * 128 * 1536;

  f32x4 acc[4][4];
  #pragma unroll
  for (int i = 0; i < 4; ++i)
    #pragma unroll
    for (int j = 0; j < 4; ++j) acc[i][j] = f32x4{0.f, 0.f, 0.f, 0.f};

  auto stage = [&](int buf, int kk) {
    unsigned short* s = smem[buf];
    #pragma unroll
    for (int it = 0; it < 4; ++it) {
      int chunk = it * 256 + tid;
      int r = chunk >> 3, cs = chunk & 7;
      gload16(Ab + (size_t)r * 1536 + kk * 64 + ((cs ^ (r & 7)) << 3), s + chunk * 8);
    }
    #pragma unroll
    for (int it = 0; it < 4; ++it) {
      int chunk = it * 256 + tid;
      int r = chunk >> 3, cs = chunk & 7;
      gload16(Bb + (size_t)r * 1536 + kk * 64 + ((cs ^ (r & 7)) << 3),
              s + 8192 + chunk * 8);
    }
  };

  stage(0, 0);
  __syncthreads();
  for (int t = 0; t < 24; ++t) {
    if (t < 23) stage((t + 1) & 1, t + 1);
    const unsigned short* s = smem[t & 1];
    #pragma unroll
    for (int ks = 0; ks < 2; ++ks) {
      s16x8 af[4], bfm[4];
      #pragma unroll
      for (int mi = 0; mi < 4; ++mi) {
        int ar = wr * 64 + mi * 16 + li;
        int ch = (ks * 4 + g) ^ (ar & 7);
        af[mi] = *(const s16x8*)(s + ar * 64 + ch * 8);
      }
      #pragma unroll
      for (int ni = 0; ni < 4; ++ni) {
        int br = wc * 64 + ni * 16 + li;
        int ch = (ks * 4 + g) ^ (br & 7);
        bfm[ni] = *(const s16x8*)(s + 8192 + br * 64 + ch * 8);
      }
      #pragma unroll
      for (int mi = 0; mi < 4; ++mi)
        #pragma unroll
        for (int ni = 0; ni < 4; ++ni)
          acc[mi][ni] = MFMA16(af[mi], bfm[ni], acc[mi][ni]);
    }
    __syncthreads();
  }

  #pragma unroll
  for (int mi = 0; mi < 4; ++mi) {
    int mrow = tm * 128 + wr * 64 + mi * 16 + g * 4;
    #pragma unroll
    for (int ni = 0; ni < 4; ++ni) {
      int ncol = tn * 128 + wc * 64 + ni * 16 + li;
      int hh = ncol >> 7, dd = ncol & 127;
      f32x4 v4 = acc[mi][ni];
      #pragma unroll
      for (int r = 0; r < 4; ++r)
        outp[((size_t)hh * 128 + (mrow + r)) * 128 + dd] = f2bf(v4[r]);
    }
  }
}

// ---------------------------------------------------------------------------
// Fused blocked local attention. 1 block = (b,h,n) 128-query tile, 8 waves x
// 16 q-rows. K/V staged cooperatively into a 32KB LDS buffer (time-shared
// K0,K1,V0,V1) via global_load_lds with XOR-swizzled source; QP then P live
// in a second 32KB region (wave-private rows, no barrier needed there).
__global__ __launch_bounds__(512, 4) void attn_kernel(
    const unsigned short* __restrict__ qb, const unsigned short* __restrict__ kb,
    const unsigned short* __restrict__ vt, const unsigned short* __restrict__ posb,
    float* __restrict__ out) {
  __shared__ __align__(16) unsigned short kv[16384];    // 32KB: K/V half-tiles
  __shared__ __align__(16) unsigned short pbuf[16384];  // 32KB: QP then P
  const int tid = threadIdx.x;
  const int w = tid >> 6, l = tid & 63, g = l >> 4, li = l & 15;
  int bid = blockIdx.x;
  bid = (bid & 7) * 192 + (bid >> 3);   // XCD swizzle: adjacent n share K/V
  const int n = bid & 31, h = (bid >> 5) % 12, b = bid / 384;
  const int qrow0 = w * 16;             // wave-local q base (block-local)

  auto stageK = [&](int half) {
    const unsigned short* kb0 =
        kb + ((size_t)(b * 12 + h) * 4224 + n * 128 + half * 128) * 128;
    #pragma unroll
    for (int it = 0; it < 4; ++it) {
      int chunk = it * 512 + tid;
      int row = chunk >> 4, sl = chunk & 15;
      gload16(kb0 + row * 128 + ((sl ^ ((row & 7) << 1)) << 3), kv + chunk * 8);
    }
  };
  auto stageV = [&](int half) {
    const unsigned short* vb0 =
        vt + (size_t)(b * 12 + h) * 128 * 4352 + n * 128 + half * 128;
    #pragma unroll
    for (int it = 0; it < 4; ++it) {
      int chunk = it * 512 + tid;
      int row = chunk >> 4, sl = chunk & 15;
      gload16(vb0 + (size_t)row * 4352 + ((sl ^ ((row & 7) << 1)) << 3),
              kv + chunk * 8);
    }
  };

  stageK(0);  // issue ASAP; QP compute below overlaps the loads

  // ---- Q fragments (A-frag: row=li, k = kt*32+g*8)
  s16x8 aq[4];
  const unsigned short* qbase =
      qb + ((size_t)(b * 12 + h) * 4096 + n * 128 + qrow0 + li) * 128 + g * 8;
  #pragma unroll
  for (int kt = 0; kt < 4; ++kt) aq[kt] = *(const s16x8*)(qbase + kt * 32);

  // ---- QP = Q * pos^T -> pbuf rows [qrow0, qrow0+16), linear [q][p]
  const unsigned short* pb = posb + (size_t)h * 128 * 128;
  #pragma unroll
  for (int pt = 0; pt < 8; ++pt) {
    f32x4 a = {0.f, 0.f, 0.f, 0.f};
    #pragma unroll
    for (int kt = 0; kt < 4; ++kt) {
      s16x8 bp = *(const s16x8*)(pb + (pt * 16 + li) * 128 + kt * 32 + g * 8);
      a = MFMA16(aq[kt], bp, a);
    }
    #pragma unroll
    for (int r = 0; r < 4; ++r)
      pbuf[(qrow0 + g * 4 + r) * 128 + pt * 16 + li] = f2bf(a[r]);
  }

  f32x4 S[16];

  auto sHalf = [&](int half) {
    #pragma unroll
    for (int c8 = 0; c8 < 8; ++c8) {
      int rowc = c8 * 16 + li;
      f32x4 s = {0.f, 0.f, 0.f, 0.f};
      #pragma unroll
      for (int kt = 0; kt < 4; ++kt) {
        int slot = (kt * 4 + g) ^ ((rowc & 7) << 1);
        s16x8 bk = *(const s16x8*)(kv + rowc * 128 + slot * 8);
        s = MFMA16(aq[kt], bk, s);
      }
      S[half * 8 + c8] = s;
    }
    #pragma unroll
    for (int c8 = 0; c8 < 8; ++c8) {
      int ct = half * 8 + c8;
      #pragma unroll
      for (int r = 0; r < 4; ++r) {
        int qq = qrow0 + g * 4 + r;       // block-local q
        int cc = ct * 16 + li;            // block-local ctx
        int p = cc - qq;
        bool win = ((unsigned)p < 128u);
        float bd = bf2f(pbuf[qq * 128 + (p & 127)]);
        float sv = S[ct][r] + (win ? bd : 0.f);
        float e2 = exp2f(sv * 0.0577078016355585f);   // (2/50)*log2(e)
        sv = 50.f - 100.f / (e2 + 1.f);               // 50*tanh(s/50), NaN-free
        bool vld = win && (n * 128 + cc >= 127);      // key t >= 0
        S[ct][r] = vld ? sv : -3e38f;
      }
    }
  };

  __syncthreads();          // K0 resident
  sHalf(0);
  __syncthreads();          // all waves done reading K0
  stageK(1);
  __syncthreads();          // K1 resident
  sHalf(1);

  // ---- softmax (full row in regs)
  float inv_[4];
  #pragma unroll
  for (int r = 0; r < 4; ++r) {
    float m_ = -3e38f;
    #pragma unroll
    for (int ct = 0; ct < 16; ++ct) m_ = fmaxf(m_, S[ct][r]);
    #pragma unroll
    for (int d = 1; d < 16; d <<= 1) m_ = fmaxf(m_, __shfl_xor(m_, d));
    float sum = 0.f;
    #pragma unroll
    for (int ct = 0; ct < 16; ++ct) {
      float e = exp2f((S[ct][r] - m_) * 1.4426950408889634f);
      S[ct][r] = e;
      sum += e;
    }
    #pragma unroll
    for (int d = 1; d < 16; d <<= 1) sum += __shfl_xor(sum, d);
    inv_[r] = 1.f / sum;
  }

  f32x4 O[8];
  #pragma unroll
  for (int jt = 0; jt < 8; ++jt) O[jt] = f32x4{0.f, 0.f, 0.f, 0.f};
  s16x8 pa[4];

  auto writeP = [&](int half) {
    #pragma unroll
    for (int c8 = 0; c8 < 8; ++c8)
      #pragma unroll
      for (int r = 0; r < 4; ++r) {
        int row = qrow0 + g * 4 + r;
        int slot = (c8 * 2 + (li >> 3)) ^ ((row & 7) << 1);
        pbuf[row * 128 + slot * 8 + (li & 7)] = f2bf(S[half * 8 + c8][r] * inv_[r]);
      }
  };
  auto readPA = [&]() {
    #pragma unroll
    for (int c = 0; c < 4; ++c) {
      int row = qrow0 + li;
      int slot = (c * 4 + g) ^ ((li & 7) << 1);
      pa[c] = *(const s16x8*)(pbuf + row * 128 + slot * 8);
    }
  };
  auto pvHalf = [&]() {
    #pragma unroll
    for (int jt = 0; jt < 8; ++jt) {
      int rowd = jt * 16 + li;
      #pragma unroll
      for (int c = 0; c < 4; ++c) {
        int slot = (c * 4 + g) ^ ((rowd & 7) << 1);
        s16x8 bv = *(const s16x8*)(kv + rowd * 128 + slot * 8);
        O[jt] = MFMA16(pa[c], bv, O[jt]);
      }
    }
  };

  __syncthreads();          // all waves done reading K1 (kv free for V0)
  stageV(0);
  writeP(0);
  readPA();
  __syncthreads();          // V0 resident
  pvHalf();
  __syncthreads();          // done reading V0
  stageV(1);
  writeP(1);
  readPA();
  __syncthreads();          // V1 resident
  pvHalf();

  // ---- store O (f32, out[b][t][h][d])
  #pragma unroll
  for (int jt = 0; jt < 8; ++jt)
    #pragma unroll
    for (int r = 0; r < 4; ++r) {
      int q = n * 128 + qrow0 + g * 4 + r;
      out[(((size_t)b * 4096 + q) * 12 + h) * 128 + jt * 16 + li] = O[jt][r];
    }
}

// ---------------------------------------------------------------------------
extern "C" void kernel_launch(void* const* d_in, const int* in_sizes, int n_in,
                              void* d_out, int out_size, void* d_ws, size_t ws_size,
                              hipStream_t stream) {
  const float* x = (const float*)d_in[0];
  const float* Wq = (const float*)d_in[1];
  const float* Wk = (const float*)d_in[2];
  const float* Wv = (const float*)d_in[3];
  const float* Wpos = (const float*)d_in[4];
  const float* pds = (const float*)d_in[5];
  float* out = (float*)d_out;

  char* ws = (char*)d_ws;
  unsigned short* xb   = (unsigned short*)(ws);              // 16384*1536 bf16
  unsigned short* Wt   = (unsigned short*)(ws + 50331648);   // 6144*1536 bf16
  unsigned short* emb  = (unsigned short*)(ws + 69206016);   // 128*1536 bf16
  unsigned short* posb = (unsigned short*)(ws + 69599232);   // 12*128*128 bf16
  unsigned short* kbuf = (unsigned short*)(ws + 69992448);   // 4*12*4224*128 bf16
  unsigned short* vtb  = (unsigned short*)(ws + 121896960);  // 4*12*128*4352 bf16
  unsigned short* qbuf = (unsigned short*)(ws + 175374336);  // 4*12*4096*128 bf16
  if (ws_size < 225705984) return;

  convert_x<<<2048, 256, 0, stream>>>((const float4*)x, (u16x4*)xb);
  wt_kernel<<<dim3(24, 24, 4), 256, 0, stream>>>(Wq, Wk, Wv, Wpos, pds, Wt);
  emb_kernel<<<128, 256, 0, stream>>>(emb);
  gemm256_kernel<<<1152, 512, 0, stream>>>(xb, Wt, qbuf, kbuf, vtb);
  gemm_kernel<<<12, 256, 0, stream>>>(emb, Wt + (size_t)4608 * 1536, posb, 12);
  attn_kernel<<<1536, 512, 0, stream>>>(qbuf, kbuf, vtb, posb, out);
}